// Round 2
// baseline (359.576 us; speedup 1.0000x reference)
//
#include <hip/hip_runtime.h>
#include <hip/hip_bf16.h>

// SelfAttention: x[B,C,E] @ W_attn[E,3E] -> qkv; causal MHA (H=16, HD=64); y @ W_proj.
// I/O is fp32 (per reference); internal compute bf16 MFMA with fp32 accumulation
// (threshold is bf16-grade: floor_eps_k=8).
// Pipeline: transpose+cast weights -> gemm_bt(QKV, fp32 A staging-cast, head-major
// scatter, V transposed) -> flash attention (mfma 16x16x32 bf16) -> gemm_bt(proj, fp32 out).

typedef unsigned short ushort_t;
typedef __attribute__((ext_vector_type(8))) short short8;
typedef __attribute__((ext_vector_type(4))) float floatx4;

#define NH   16
#define SEQ  2048
#define EMB  1024
#define HDIM 64

__device__ __forceinline__ ushort_t f2bf(float f) {
    union { float f; unsigned u; } v; v.f = f;
    unsigned r = (v.u + 0x7fffu + ((v.u >> 16) & 1u)) >> 16;  // RNE
    return (ushort_t)r;
}

// ---------------- transpose + fp32->bf16 cast (dims multiples of 32) ----------------
__global__ void transpose_cast_k(const float* __restrict__ in, ushort_t* __restrict__ out,
                                 int R, int Cc) {
    __shared__ ushort_t tile[32][33];
    int x  = blockIdx.x * 32 + threadIdx.x;   // input col
    int y0 = blockIdx.y * 32;                 // input row base
#pragma unroll
    for (int i = 0; i < 32; i += 8)
        tile[threadIdx.y + i][threadIdx.x] = f2bf(in[(size_t)(y0 + threadIdx.y + i) * Cc + x]);
    __syncthreads();
    int xo = blockIdx.y * 32 + threadIdx.x;   // output col = input row
    int yo = blockIdx.x * 32;                 // output row base = input col
#pragma unroll
    for (int i = 0; i < 32; i += 8)
        out[(size_t)(yo + threadIdx.y + i) * R + xo] = tile[threadIdx.x][threadIdx.y + i];
}

// ---------------- GEMM: C[m][n] = sum_k A[m][k] * Bt[n][k] ----------------
// 128x128 tile / block (256 thr = 4 waves, 2x2 wave grid, 4x4 16x16 micro each).
// A_F32=1: A is fp32, cast to bf16 during LDS staging. Bt always bf16.
// EPI=0: fp32 store to O0[m*N+n]. EPI=1: bf16 QKV scatter (Q,K head-major; V transposed).
template<int EPI, int A_F32>
__global__ __launch_bounds__(256) void gemm_bt(const void* __restrict__ Av,
                                               const ushort_t* __restrict__ Bt,
                                               void* __restrict__ O0v,
                                               ushort_t* __restrict__ O1,
                                               ushort_t* __restrict__ O2,
                                               int M, int N, int K) {
    __shared__ ushort_t As[128 * 72];   // row stride 72 (pad +8 bf16): 2-way banks = free
    __shared__ ushort_t Bs[128 * 72];
    const int tid  = threadIdx.x;
    const int wv   = tid >> 6, lane = tid & 63, quad = lane >> 4, l15 = lane & 15;
    const int wm   = wv >> 1, wn = wv & 1;
    const int bm   = blockIdx.x, bn = blockIdx.y;

    floatx4 acc[4][4];
#pragma unroll
    for (int i = 0; i < 4; i++)
#pragma unroll
        for (int j = 0; j < 4; j++) acc[i][j] = (floatx4){0.f, 0.f, 0.f, 0.f};

    for (int kt = 0; kt < K; kt += 64) {
#pragma unroll
        for (int i = 0; i < 4; i++) {            // 1024 16B-chunks, 4/thread
            int c = tid + i * 256; int row = c >> 3; int kg = c & 7;
            if (A_F32) {
                const float* Af = (const float*)Av + (size_t)(bm * 128 + row) * K + kt + kg * 8;
                float4 v0 = *(const float4*)Af;
                float4 v1 = *(const float4*)(Af + 4);
                short8 t;
                t[0] = (short)f2bf(v0.x); t[1] = (short)f2bf(v0.y);
                t[2] = (short)f2bf(v0.z); t[3] = (short)f2bf(v0.w);
                t[4] = (short)f2bf(v1.x); t[5] = (short)f2bf(v1.y);
                t[6] = (short)f2bf(v1.z); t[7] = (short)f2bf(v1.w);
                *(short8*)&As[row * 72 + kg * 8] = t;
            } else {
                const ushort_t* Ab = (const ushort_t*)Av;
                *(uint4*)&As[row * 72 + kg * 8] =
                    *(const uint4*)&Ab[(size_t)(bm * 128 + row) * K + kt + kg * 8];
            }
            *(uint4*)&Bs[row * 72 + kg * 8] =
                *(const uint4*)&Bt[(size_t)(bn * 128 + row) * K + kt + kg * 8];
        }
        __syncthreads();
#pragma unroll
        for (int ks = 0; ks < 2; ks++) {
            short8 af[4], bf[4];
#pragma unroll
            for (int i = 0; i < 4; i++)
                af[i] = *(const short8*)&As[(wm * 64 + i * 16 + l15) * 72 + ks * 32 + quad * 8];
#pragma unroll
            for (int j = 0; j < 4; j++)
                bf[j] = *(const short8*)&Bs[(wn * 64 + j * 16 + l15) * 72 + ks * 32 + quad * 8];
#pragma unroll
            for (int i = 0; i < 4; i++)
#pragma unroll
                for (int j = 0; j < 4; j++)
                    acc[i][j] = __builtin_amdgcn_mfma_f32_16x16x32_bf16(af[i], bf[j], acc[i][j], 0, 0, 0);
        }
        __syncthreads();
    }

#pragma unroll
    for (int i = 0; i < 4; i++)
#pragma unroll
        for (int j = 0; j < 4; j++)
#pragma unroll
            for (int r = 0; r < 4; r++) {
                int row = bm * 128 + wm * 64 + i * 16 + quad * 4 + r;   // C/D: row=quad*4+reg
                int col = bn * 128 + wn * 64 + j * 16 + l15;            //      col=lane&15
                if (EPI == 0) {
                    ((float*)O0v)[(size_t)row * N + col] = acc[i][j][r];
                } else {
                    ushort_t v = f2bf(acc[i][j][r]);
                    int b = row >> 11, c = row & 2047;
                    int which = col >> 10, nn = col & 1023;
                    int h = nn >> 6, d = nn & 63;
                    size_t bh = (size_t)b * NH + h;
                    if (which == 0)      ((ushort_t*)O0v)[(bh * SEQ + c) * HDIM + d] = v;  // Q[bh][c][d]
                    else if (which == 1) O1[(bh * SEQ + c) * HDIM + d] = v;                // K[bh][c][d]
                    else                 O2[(bh * HDIM + d) * SEQ + c] = v;                // Vt[bh][d][c]
                }
            }
}

// ---------------- flash attention ----------------
// grid (BH=64, C/64=32); block 256 = 4 waves; wave w owns q rows [qb*64+16w, +16).
__global__ __launch_bounds__(256) void attn_k(const ushort_t* __restrict__ Qg,
                                              const ushort_t* __restrict__ Kg,
                                              const ushort_t* __restrict__ Vtg,
                                              ushort_t* __restrict__ Y) {
    __shared__ ushort_t Ks[64 * 72];      // [key][d]
    __shared__ ushort_t Vs[64 * 72];      // [d][key]  (V pre-transposed in ws)
    __shared__ ushort_t Ps[4][16 * 72];   // per-wave P tile [q_local][key]
    const int tid  = threadIdx.x;
    const int wv   = tid >> 6, lane = tid & 63, quad = lane >> 4, l15 = lane & 15;
    const int bh   = blockIdx.x, qb = blockIdx.y;
    const int qrow0 = qb * 64 + wv * 16;

    short8 qf[2];
#pragma unroll
    for (int ks = 0; ks < 2; ks++)        // A-layout: m=l15 row, k=quad*8+j contiguous
        qf[ks] = *(const short8*)&Qg[((size_t)bh * SEQ + qrow0 + l15) * HDIM + ks * 32 + quad * 8];

    floatx4 o[4];
#pragma unroll
    for (int i = 0; i < 4; i++) o[i] = (floatx4){0.f, 0.f, 0.f, 0.f};
    float m_i[4] = {-1e30f, -1e30f, -1e30f, -1e30f};
    float l_i[4] = {0.f, 0.f, 0.f, 0.f};

    for (int j = 0; j <= qb; j++) {
#pragma unroll
        for (int i = 0; i < 2; i++) {     // 512 16B-chunks per tile pair, 2/thread
            int c = tid + i * 256; int row = c >> 3; int kg = c & 7;
            *(uint4*)&Ks[row * 72 + kg * 8] =
                *(const uint4*)&Kg[((size_t)bh * SEQ + j * 64 + row) * HDIM + kg * 8];
            *(uint4*)&Vs[row * 72 + kg * 8] =
                *(const uint4*)&Vtg[((size_t)bh * HDIM + row) * SEQ + j * 64 + kg * 8];
        }
        __syncthreads();

        // S = Q K^T  (16 q rows x 64 keys per wave)
        floatx4 s4[4];
#pragma unroll
        for (int ns = 0; ns < 4; ns++) {
            floatx4 acc = (floatx4){0.f, 0.f, 0.f, 0.f};
#pragma unroll
            for (int ks = 0; ks < 2; ks++) {
                short8 bf = *(const short8*)&Ks[(ns * 16 + l15) * 72 + ks * 32 + quad * 8];
                acc = __builtin_amdgcn_mfma_f32_16x16x32_bf16(qf[ks], bf, acc, 0, 0, 0);
            }
            s4[ns] = acc;
        }

        float sv[4][4];
        const bool mask = (j == qb);
#pragma unroll
        for (int ns = 0; ns < 4; ns++)
#pragma unroll
            for (int r = 0; r < 4; r++) {
                float v = s4[ns][r] * 0.125f;            // 1/sqrt(64)
                if (mask) {
                    int qa = qrow0 + quad * 4 + r;
                    int ka = j * 64 + ns * 16 + l15;
                    if (ka > qa) v = -1e30f;
                }
                sv[ns][r] = v;
            }

        // online softmax per row r (row lives on the 16 lanes of this quad)
#pragma unroll
        for (int r = 0; r < 4; r++) {
            float mx = fmaxf(fmaxf(sv[0][r], sv[1][r]), fmaxf(sv[2][r], sv[3][r]));
#pragma unroll
            for (int off = 1; off < 16; off <<= 1) mx = fmaxf(mx, __shfl_xor(mx, off));
            float m_new = fmaxf(m_i[r], mx);
            float alpha = __expf(m_i[r] - m_new);
            float p[4], rs = 0.f;
#pragma unroll
            for (int ns = 0; ns < 4; ns++) { p[ns] = __expf(sv[ns][r] - m_new); rs += p[ns]; }
#pragma unroll
            for (int off = 1; off < 16; off <<= 1) rs += __shfl_xor(rs, off);
            l_i[r] = l_i[r] * alpha + rs;
            m_i[r] = m_new;
#pragma unroll
            for (int ds = 0; ds < 4; ds++) o[ds][r] *= alpha;   // same quad/reg row mapping
#pragma unroll
            for (int ns = 0; ns < 4; ns++)                       // C-layout -> LDS
                Ps[wv][(quad * 4 + r) * 72 + ns * 16 + l15] = f2bf(p[ns]);
        }

        // O += P V   (P re-read in A-layout; Vs rows are d, contiguous keys)
#pragma unroll
        for (int ds = 0; ds < 4; ds++)
#pragma unroll
            for (int ks = 0; ks < 2; ks++) {
                short8 af = *(const short8*)&Ps[wv][l15 * 72 + ks * 32 + quad * 8];
                short8 bf = *(const short8*)&Vs[(ds * 16 + l15) * 72 + ks * 32 + quad * 8];
                o[ds] = __builtin_amdgcn_mfma_f32_16x16x32_bf16(af, bf, o[ds], 0, 0, 0);
            }
        __syncthreads();
    }

    const int b = bh >> 4, h = bh & 15;
#pragma unroll
    for (int ds = 0; ds < 4; ds++)
#pragma unroll
        for (int r = 0; r < 4; r++) {
            int c = qrow0 + quad * 4 + r;
            int d = ds * 16 + l15;
            float val = o[ds][r] / l_i[r];
            Y[((size_t)(b * SEQ + c)) * EMB + h * HDIM + d] = f2bf(val);   // [b][c][h*64+d]
        }
}

// ---------------- launch ----------------
extern "C" void kernel_launch(void* const* d_in, const int* in_sizes, int n_in,
                              void* d_out, int out_size, void* d_ws, size_t ws_size,
                              hipStream_t stream) {
    const float* x      = (const float*)d_in[0];   // [8192][1024] fp32
    const float* W_attn = (const float*)d_in[1];   // [1024][3072] fp32
    const float* W_proj = (const float*)d_in[2];   // [1024][1024] fp32

    char* ws = (char*)d_ws;
    ushort_t* Wt_attn = (ushort_t*)(ws);                 // [3072][1024] bf16  6.3 MB
    ushort_t* Wt_proj = (ushort_t*)(ws + 6291456);       // [1024][1024] bf16  2.1 MB
    ushort_t* Qb      = (ushort_t*)(ws + 8388608);       // [64][2048][64]    16.8 MB
    ushort_t* Kb      = (ushort_t*)(ws + 25165824);      // [64][2048][64]
    ushort_t* Vt      = (ushort_t*)(ws + 41943040);      // [64][64][2048]
    ushort_t* Yb      = (ushort_t*)(ws + 58720256);      // [8192][1024]
    // total ws use: 75,497,472 B

    transpose_cast_k<<<dim3(3072 / 32, 1024 / 32), dim3(32, 8), 0, stream>>>(W_attn, Wt_attn, 1024, 3072);
    transpose_cast_k<<<dim3(1024 / 32, 1024 / 32), dim3(32, 8), 0, stream>>>(W_proj, Wt_proj, 1024, 1024);
    gemm_bt<1, 1><<<dim3(8192 / 128, 3072 / 128), 256, 0, stream>>>(x, Wt_attn, Qb, Kb, Vt, 8192, 3072, 1024);
    attn_k<<<dim3(64, 32), 256, 0, stream>>>(Qb, Kb, Vt, Yb);
    gemm_bt<0, 0><<<dim3(8192 / 128, 1024 / 128), 256, 0, stream>>>(Yb, Wt_proj, d_out,
                                                                    nullptr, nullptr, 8192, 1024, 1024);
}

// Round 3
// 305.345 us; speedup vs baseline: 1.1776x; 1.1776x over previous
//
#include <hip/hip_runtime.h>
#include <hip/hip_bf16.h>

// SelfAttention: x[B,C,E] @ W_attn[E,3E] -> qkv; causal MHA (H=16, HD=64); y @ W_proj.
// fp32 I/O, bf16 MFMA internals. R2: (a) GEMM uses global_load_lds width=16 with
// XOR-swizzled LDS (no pad; swizzle in the per-lane global column), A pre-cast to bf16.
// (b) attn computes S^T = K Q^T so each softmax row is one lane (q = lane&15):
// in-lane folds + 2 cross-quad shuffles, per-lane m/l state, P written as ds_write_b64.

typedef unsigned short ushort_t;
typedef __attribute__((ext_vector_type(8))) short short8;
typedef __attribute__((ext_vector_type(4))) float floatx4;

#define NH   16
#define SEQ  2048
#define EMB  1024
#define HDIM 64

__device__ __forceinline__ ushort_t f2bf(float f) {
    union { float f; unsigned u; } v; v.f = f;
    unsigned r = (v.u + 0x7fffu + ((v.u >> 16) & 1u)) >> 16;  // RNE
    return (ushort_t)r;
}

#if defined(__has_builtin) && __has_builtin(__builtin_amdgcn_global_load_lds)
#define HAS_GLL 1
__device__ __forceinline__ void gload16(const ushort_t* g, ushort_t* l) {
    __builtin_amdgcn_global_load_lds((const __attribute__((address_space(1))) void*)g,
                                     (__attribute__((address_space(3))) void*)l, 16, 0, 0);
}
#else
#define HAS_GLL 0
#endif

// ---------------- fp32 -> bf16 cast (8 elems/thread) ----------------
__global__ __launch_bounds__(256) void cast_k(const float* __restrict__ in,
                                              ushort_t* __restrict__ out) {
    int i = blockIdx.x * 256 + threadIdx.x;
    float4 v0 = ((const float4*)in)[i * 2];
    float4 v1 = ((const float4*)in)[i * 2 + 1];
    short8 t;
    t[0] = (short)f2bf(v0.x); t[1] = (short)f2bf(v0.y);
    t[2] = (short)f2bf(v0.z); t[3] = (short)f2bf(v0.w);
    t[4] = (short)f2bf(v1.x); t[5] = (short)f2bf(v1.y);
    t[6] = (short)f2bf(v1.z); t[7] = (short)f2bf(v1.w);
    ((short8*)out)[i] = t;
}

// ---------------- transpose + fp32->bf16 cast ----------------
__global__ void transpose_cast_k(const float* __restrict__ in, ushort_t* __restrict__ out,
                                 int R, int Cc) {
    __shared__ ushort_t tile[32][33];
    int x  = blockIdx.x * 32 + threadIdx.x;
    int y0 = blockIdx.y * 32;
#pragma unroll
    for (int i = 0; i < 32; i += 8)
        tile[threadIdx.y + i][threadIdx.x] = f2bf(in[(size_t)(y0 + threadIdx.y + i) * Cc + x]);
    __syncthreads();
    int xo = blockIdx.y * 32 + threadIdx.x;
    int yo = blockIdx.x * 32;
#pragma unroll
    for (int i = 0; i < 32; i += 8)
        out[(size_t)(yo + threadIdx.y + i) * R + xo] = tile[threadIdx.x][threadIdx.y + i];
}

// ---------------- GEMM: C[m][n] = sum_k A[m][k] * Bt[n][k] (both bf16) ----------------
// 128x128 tile, 256 thr, BK=64. LDS unpadded 64/row, XOR-swizzled: slot (row, kgs)
// holds global kgroup kgs ^ (row&7). Staged via global_load_lds (1KB per call: 8 rows).
// EPI=0: fp32 store. EPI=1: bf16 QKV scatter (Q,K head-major; V transposed).
template<int EPI>
__global__ __launch_bounds__(256) void gemm_bt(const ushort_t* __restrict__ A,
                                               const ushort_t* __restrict__ Bt,
                                               void* __restrict__ O0v,
                                               ushort_t* __restrict__ O1,
                                               ushort_t* __restrict__ O2,
                                               int M, int N, int K) {
    __shared__ __align__(16) ushort_t As[128 * 64];
    __shared__ __align__(16) ushort_t Bs[128 * 64];
    const int tid  = threadIdx.x;
    const int wv   = tid >> 6, lane = tid & 63, quad = lane >> 4, l15 = lane & 15;
    const int wm   = wv >> 1, wn = wv & 1;
    const int bm   = blockIdx.x, bn = blockIdx.y;
    const int lrow = lane >> 3;                 // 0..7 within an 8-row DMA chunk
    const int kg   = (lane & 7) ^ (lrow & 7);   // global kgroup feeding swizzled slot lane&7
    const int sw   = l15 & 7;                   // read-side swizzle key (row&7 == l15&7)

    floatx4 acc[4][4];
#pragma unroll
    for (int i = 0; i < 4; i++)
#pragma unroll
        for (int j = 0; j < 4; j++) acc[i][j] = (floatx4){0.f, 0.f, 0.f, 0.f};

    for (int kt = 0; kt < K; kt += 64) {
#pragma unroll
        for (int it = 0; it < 4; it++) {        // 4 chunks of 8 rows per wave (32 rows/it)
            int r0 = it * 32 + wv * 8;
            const ushort_t* ga = &A [(size_t)(bm * 128 + r0 + lrow) * K + kt + kg * 8];
            const ushort_t* gb = &Bt[(size_t)(bn * 128 + r0 + lrow) * K + kt + kg * 8];
#if HAS_GLL
            gload16(ga, &As[r0 * 64]);
            gload16(gb, &Bs[r0 * 64]);
#else
            *(uint4*)&As[(r0 + lrow) * 64 + (lane & 7) * 8] = *(const uint4*)ga;
            *(uint4*)&Bs[(r0 + lrow) * 64 + (lane & 7) * 8] = *(const uint4*)gb;
#endif
        }
        __syncthreads();
#pragma unroll
        for (int ks = 0; ks < 2; ks++) {
            short8 af[4], bf[4];
#pragma unroll
            for (int i = 0; i < 4; i++)
                af[i] = *(const short8*)&As[(wm * 64 + i * 16 + l15) * 64 + (((ks * 4 + quad) ^ sw) * 8)];
#pragma unroll
            for (int j = 0; j < 4; j++)
                bf[j] = *(const short8*)&Bs[(wn * 64 + j * 16 + l15) * 64 + (((ks * 4 + quad) ^ sw) * 8)];
#pragma unroll
            for (int i = 0; i < 4; i++)
#pragma unroll
                for (int j = 0; j < 4; j++)
                    acc[i][j] = __builtin_amdgcn_mfma_f32_16x16x32_bf16(af[i], bf[j], acc[i][j], 0, 0, 0);
        }
        __syncthreads();
    }

#pragma unroll
    for (int i = 0; i < 4; i++)
#pragma unroll
        for (int j = 0; j < 4; j++)
#pragma unroll
            for (int r = 0; r < 4; r++) {
                int row = bm * 128 + wm * 64 + i * 16 + quad * 4 + r;   // C/D: row=quad*4+reg
                int col = bn * 128 + wn * 64 + j * 16 + l15;            //      col=lane&15
                if (EPI == 0) {
                    ((float*)O0v)[(size_t)row * N + col] = acc[i][j][r];
                } else {
                    ushort_t v = f2bf(acc[i][j][r]);
                    int b = row >> 11, c = row & 2047;
                    int which = col >> 10, nn = col & 1023;
                    int h = nn >> 6, d = nn & 63;
                    size_t bh = (size_t)b * NH + h;
                    if (which == 0)      ((ushort_t*)O0v)[(bh * SEQ + c) * HDIM + d] = v;  // Q[bh][c][d]
                    else if (which == 1) O1[(bh * SEQ + c) * HDIM + d] = v;                // K[bh][c][d]
                    else                 O2[(bh * HDIM + d) * SEQ + c] = v;                // Vt[bh][d][c]
                }
            }
}

// ---------------- flash attention (S^T scheme) ----------------
// grid (BH=64, C/64=32); 4 waves; wave w owns q rows [qb*64+16w, +16).
// S^T = K Q^T: C-layout row=key(quad*4+r), col=q(l15) -> softmax state per lane (q=l15).
__global__ __launch_bounds__(256) void attn_k(const ushort_t* __restrict__ Qg,
                                              const ushort_t* __restrict__ Kg,
                                              const ushort_t* __restrict__ Vtg,
                                              ushort_t* __restrict__ Y) {
    __shared__ __align__(16) ushort_t Ks[64 * 72];      // [key][d]
    __shared__ __align__(16) ushort_t Vs[64 * 72];      // [d][key]
    __shared__ __align__(16) ushort_t Ps[4][16 * 80];   // per-wave P [q][key], stride 80
    const int tid  = threadIdx.x;
    const int wv   = tid >> 6, lane = tid & 63, quad = lane >> 4, l15 = lane & 15;
    const int bh   = blockIdx.x, qb = blockIdx.y;
    const int qrow0 = qb * 64 + wv * 16;
    const int q_abs = qrow0 + l15;                      // this lane's softmax row

    short8 qf[2];
#pragma unroll
    for (int ks = 0; ks < 2; ks++)
        qf[ks] = *(const short8*)&Qg[((size_t)bh * SEQ + qrow0 + l15) * HDIM + ks * 32 + quad * 8];

    floatx4 o[4];
#pragma unroll
    for (int i = 0; i < 4; i++) o[i] = (floatx4){0.f, 0.f, 0.f, 0.f};
    float m_i = -1e30f, l_i = 0.f;

    for (int j = 0; j <= qb; j++) {
#pragma unroll
        for (int i = 0; i < 2; i++) {
            int c = tid + i * 256; int row = c >> 3; int kgx = c & 7;
            *(uint4*)&Ks[row * 72 + kgx * 8] =
                *(const uint4*)&Kg[((size_t)bh * SEQ + j * 64 + row) * HDIM + kgx * 8];
            *(uint4*)&Vs[row * 72 + kgx * 8] =
                *(const uint4*)&Vtg[((size_t)bh * HDIM + row) * SEQ + j * 64 + kgx * 8];
        }
        __syncthreads();

        // S^T tile: st[ns][r] = S[key = j*64+ns*16+quad*4+r][q = q_abs]
        floatx4 st[4];
#pragma unroll
        for (int ns = 0; ns < 4; ns++) {
            floatx4 acc = (floatx4){0.f, 0.f, 0.f, 0.f};
#pragma unroll
            for (int ks = 0; ks < 2; ks++) {
                short8 af = *(const short8*)&Ks[(ns * 16 + l15) * 72 + ks * 32 + quad * 8];
                acc = __builtin_amdgcn_mfma_f32_16x16x32_bf16(af, qf[ks], acc, 0, 0, 0);
            }
            st[ns] = acc;
        }

        const bool edge = (j == qb);
        float sv[4][4];
#pragma unroll
        for (int ns = 0; ns < 4; ns++)
#pragma unroll
            for (int r = 0; r < 4; r++) {
                float v = st[ns][r] * 0.125f;            // 1/sqrt(64)
                if (edge) {
                    int ka = j * 64 + ns * 16 + quad * 4 + r;
                    if (ka > q_abs) v = -1e30f;
                }
                sv[ns][r] = v;
            }

        // in-lane max over 16 scores, then cross-quad (2 shuffles)
        float mx = sv[0][0];
#pragma unroll
        for (int ns = 0; ns < 4; ns++)
#pragma unroll
            for (int r = 0; r < 4; r++) mx = fmaxf(mx, sv[ns][r]);
        mx = fmaxf(mx, __shfl_xor(mx, 16));
        mx = fmaxf(mx, __shfl_xor(mx, 32));

        float m_new = fmaxf(m_i, mx);
        float alpha = __expf(m_i - m_new);
        m_i = m_new;

        float rs = 0.f;
#pragma unroll
        for (int ns = 0; ns < 4; ns++) {
            float p0 = __expf(sv[ns][0] - m_new);
            float p1 = __expf(sv[ns][1] - m_new);
            float p2 = __expf(sv[ns][2] - m_new);
            float p3 = __expf(sv[ns][3] - m_new);
            rs += (p0 + p1) + (p2 + p3);
            unsigned u0 = (unsigned)f2bf(p0) | ((unsigned)f2bf(p1) << 16);
            unsigned u1 = (unsigned)f2bf(p2) | ((unsigned)f2bf(p3) << 16);
            uint2 w; w.x = u0; w.y = u1;                  // keys quad*4..+3 of group ns
            *(uint2*)&Ps[wv][l15 * 80 + ns * 16 + quad * 4] = w;
        }
        rs += __shfl_xor(rs, 16);
        rs += __shfl_xor(rs, 32);
        l_i = l_i * alpha + rs;

        // rescale O (C-layout q = quad*4+r; alpha lives at lane l15=q)
#pragma unroll
        for (int r = 0; r < 4; r++) {
            float ar = __shfl(alpha, quad * 4 + r, 64);
#pragma unroll
            for (int ds = 0; ds < 4; ds++) o[ds][r] *= ar;
        }

        // O += P V   (A-frag: m=q=l15, k=key contiguous; B-frag: n=d=l15, k=key)
#pragma unroll
        for (int ds = 0; ds < 4; ds++)
#pragma unroll
            for (int ks = 0; ks < 2; ks++) {
                short8 af = *(const short8*)&Ps[wv][l15 * 80 + ks * 32 + quad * 8];
                short8 bf = *(const short8*)&Vs[(ds * 16 + l15) * 72 + ks * 32 + quad * 8];
                o[ds] = __builtin_amdgcn_mfma_f32_16x16x32_bf16(af, bf, o[ds], 0, 0, 0);
            }
        __syncthreads();
    }

    const int b = bh >> 4, h = bh & 15;
    float inv = 1.0f / l_i;
#pragma unroll
    for (int r = 0; r < 4; r++) {
        float ir = __shfl(inv, quad * 4 + r, 64);
        int c = qrow0 + quad * 4 + r;
#pragma unroll
        for (int ds = 0; ds < 4; ds++) {
            int d = ds * 16 + l15;
            Y[((size_t)(b * SEQ + c)) * EMB + h * HDIM + d] = f2bf(o[ds][r] * ir);
        }
    }
}

// ---------------- launch ----------------
extern "C" void kernel_launch(void* const* d_in, const int* in_sizes, int n_in,
                              void* d_out, int out_size, void* d_ws, size_t ws_size,
                              hipStream_t stream) {
    const float* x      = (const float*)d_in[0];   // [8192][1024] fp32
    const float* W_attn = (const float*)d_in[1];   // [1024][3072] fp32
    const float* W_proj = (const float*)d_in[2];   // [1024][1024] fp32

    char* ws = (char*)d_ws;
    ushort_t* Wt_attn = (ushort_t*)(ws);                 // [3072][1024] bf16  6.3 MB
    ushort_t* Wt_proj = (ushort_t*)(ws + 6291456);       // [1024][1024] bf16  2.1 MB
    ushort_t* Xb      = (ushort_t*)(ws + 8388608);       // [8192][1024] bf16 16.8 MB
    ushort_t* Yb      = Xb;                              // aliased: Xb dead before attn writes Yb
    ushort_t* Qb      = (ushort_t*)(ws + 25165824);      // [64][2048][64]
    ushort_t* Kb      = (ushort_t*)(ws + 41943040);      // [64][2048][64]
    ushort_t* Vt      = (ushort_t*)(ws + 58720256);      // [64][64][2048]
    // total ws use: 75,497,472 B (same as round 2)

    cast_k<<<4096, 256, 0, stream>>>(x, Xb);
    transpose_cast_k<<<dim3(3072 / 32, 1024 / 32), dim3(32, 8), 0, stream>>>(W_attn, Wt_attn, 1024, 3072);
    transpose_cast_k<<<dim3(1024 / 32, 1024 / 32), dim3(32, 8), 0, stream>>>(W_proj, Wt_proj, 1024, 1024);
    gemm_bt<1><<<dim3(8192 / 128, 3072 / 128), 256, 0, stream>>>(Xb, Wt_attn, Qb, Kb, Vt, 8192, 3072, 1024);
    attn_k<<<dim3(64, 32), 256, 0, stream>>>(Qb, Kb, Vt, Yb);
    gemm_bt<0><<<dim3(8192 / 128, 1024 / 128), 256, 0, stream>>>(Yb, Wt_proj, d_out,
                                                                 nullptr, nullptr, 8192, 1024, 1024);
}